// Round 6
// baseline (110.717 us; speedup 1.0000x reference)
//
#include <hip/hip_runtime.h>

// SimpleMHA2D: B=32, S=HW=1024, C=KV=1024, N=16, K=V=64, fp32.
//  K1: qk[c][n] = sum_k k_kernel[c][n*64+k]*q[n][k];  qb[n] = sum_k k_bias*q
//  K2 (fused): per (b, 128-row chunk): logits -> chunk softmax (m_ch, l_ch, e)
//              -> wp[b][ch][n][c] = sum_s e*x.  Deferred global rescale in K3.
//  K3: out[b][n][v] = (sum_ch fac_ch*wp_ch . vk)/ (sum_ch fac_ch*l_ch) + vb,
//      fac_ch = exp(m_ch - max_ch m_ch).

// ---------------- K1: fold query into k_kernel ----------------
__global__ __launch_bounds__(256) void k_qk(const float* __restrict__ kk,
                                            const float* __restrict__ q,
                                            const float* __restrict__ kb,
                                            float* __restrict__ qk,
                                            float* __restrict__ qb) {
  const int gid = blockIdx.x * 256 + threadIdx.x;   // 16384 = 1024c * 16n
  const int c = gid >> 4, n = gid & 15;
  float a = 0.f;
#pragma unroll
  for (int k4 = 0; k4 < 64; k4 += 4) {
    const float4 kv = *(const float4*)(kk + (size_t)c * 1024 + n * 64 + k4);
    const float4 qv = *(const float4*)(q + n * 64 + k4);
    a += kv.x * qv.x + kv.y * qv.y + kv.z * qv.z + kv.w * qv.w;
  }
  qk[gid] = a;  // layout [c][n], gid == c*16+n
  if (blockIdx.x == 0 && threadIdx.x < 16) {
    float s = 0.f;
    for (int k = 0; k < 64; k++) s += kb[threadIdx.x * 64 + k] * q[threadIdx.x * 64 + k];
    qb[threadIdx.x] = s;
  }
}

// ---------------- K2: fused logits + chunk softmax + weighted sum ----------------
// Block = (b, ch): 256 blocks, 1024 thr (16 waves). LDS: qkt 64KB (read-only
// after staging) + lt 8.25KB logits. No LDS overlay/reuse anywhere.
__global__ __launch_bounds__(1024) void k_fused(const float* __restrict__ x,
                                                const float* __restrict__ qk,
                                                const float* __restrict__ qb,
                                                float* __restrict__ es,
                                                float* __restrict__ mch,
                                                float* __restrict__ lch,
                                                float* __restrict__ wp) {
  __shared__ float qkt[16384];     // qkt[nq][c][e], never written after staging
  __shared__ float lt[16 * 132];   // lt[n][row], pad 132 -> 2-way banks max
  const int tid = threadIdx.x;
  const int lane = tid & 63;
  const int wid = tid >> 6;
  const int blk = blockIdx.x;          // b*8 + ch
  const int srow0 = blk * 128;         // global row base (b*1024 + ch*128)

  // stage qk[c][n] -> qkt[nq][c][e]
#pragma unroll
  for (int it = 0; it < 4; ++it) {
    const int g = it * 1024 + tid;
    const float4 v = *(const float4*)(qk + (size_t)g * 4);
    *(float4*)&qkt[(g & 3) * 4096 + (g >> 2) * 4] = v;
  }
  __syncthreads();

  // ---- Phase A: logits for 128 rows (2 sweeps x 16 waves x 4 rows) ----
#pragma unroll 1
  for (int sweep = 0; sweep < 2; ++sweep) {
    const int rloc = sweep * 64 + wid * 4;   // chunk-local row of this wave
    const float* xw = x + (size_t)(srow0 + rloc) * 1024 + lane;

    float acc[4][16];
#pragma unroll
    for (int r = 0; r < 4; ++r)
#pragma unroll
      for (int n = 0; n < 16; ++n) acc[r][n] = 0.f;

    float xa[4], xb[4];
#pragma unroll
    for (int r = 0; r < 4; ++r) xa[r] = xw[(size_t)r * 1024];

#pragma unroll 1
    for (int st = 0; st < 16; st += 2) {
#pragma unroll
      for (int r = 0; r < 4; ++r) xb[r] = xw[(size_t)r * 1024 + (st + 1) * 64];
      {
        const int c4 = (st * 64 + lane) * 4;
#pragma unroll
        for (int nq = 0; nq < 4; ++nq) {
          const float4 qv = *(const float4*)&qkt[nq * 4096 + c4];
#pragma unroll
          for (int r = 0; r < 4; ++r) {
            acc[r][nq * 4 + 0] += xa[r] * qv.x;
            acc[r][nq * 4 + 1] += xa[r] * qv.y;
            acc[r][nq * 4 + 2] += xa[r] * qv.z;
            acc[r][nq * 4 + 3] += xa[r] * qv.w;
          }
        }
      }
      if (st + 2 < 16) {
#pragma unroll
        for (int r = 0; r < 4; ++r) xa[r] = xw[(size_t)r * 1024 + (st + 2) * 64];
      }
      {
        const int c4 = ((st + 1) * 64 + lane) * 4;
#pragma unroll
        for (int nq = 0; nq < 4; ++nq) {
          const float4 qv = *(const float4*)&qkt[nq * 4096 + c4];
#pragma unroll
          for (int r = 0; r < 4; ++r) {
            acc[r][nq * 4 + 0] += xb[r] * qv.x;
            acc[r][nq * 4 + 1] += xb[r] * qv.y;
            acc[r][nq * 4 + 2] += xb[r] * qv.z;
            acc[r][nq * 4 + 3] += xb[r] * qv.w;
          }
        }
      }
    }

    // register-only reduce-scatter butterfly (validated in R5)
    const int b0 = lane & 1, b1 = (lane >> 1) & 1;
    const int b2 = (lane >> 2) & 1, b3 = (lane >> 3) & 1;
    float f[4];
#pragma unroll
    for (int r = 0; r < 4; ++r) {
      float u[8];
#pragma unroll
      for (int m = 0; m < 8; ++m) {
        const float keep = b0 ? acc[r][2 * m + 1] : acc[r][2 * m];
        const float give = b0 ? acc[r][2 * m]     : acc[r][2 * m + 1];
        u[m] = keep + __shfl_xor(give, 1);
      }
      float w[4];
#pragma unroll
      for (int p = 0; p < 4; ++p) {
        const float keep = b1 ? u[2 * p + 1] : u[2 * p];
        const float give = b1 ? u[2 * p]     : u[2 * p + 1];
        w[p] = keep + __shfl_xor(give, 2);
      }
      float z[2];
#pragma unroll
      for (int qq = 0; qq < 2; ++qq) {
        const float keep = b2 ? w[2 * qq + 1] : w[2 * qq];
        const float give = b2 ? w[2 * qq]     : w[2 * qq + 1];
        z[qq] = keep + __shfl_xor(give, 4);
      }
      {
        const float keep = b3 ? z[1] : z[0];
        const float give = b3 ? z[0] : z[1];
        float t = keep + __shfl_xor(give, 8);
        t += __shfl_xor(t, 16);
        t += __shfl_xor(t, 32);
        f[r] = t;
      }
    }
    const int rsel = lane >> 4;
    float val = (rsel == 0) ? f[0] : (rsel == 1) ? f[1] : (rsel == 2) ? f[2] : f[3];
    val += qb[lane & 15];
    lt[(lane & 15) * 132 + rloc + rsel] = val;
  }
  __syncthreads();

  // ---- Phase B: chunk softmax per n (wave wid <-> n) ----
  {
    const float v0 = lt[wid * 132 + 2 * lane];
    const float v1 = lt[wid * 132 + 2 * lane + 1];
    float m = fmaxf(v0, v1);
#pragma unroll
    for (int d = 1; d < 64; d <<= 1) m = fmaxf(m, __shfl_xor(m, d));
    const float e0 = __expf(v0 - m), e1 = __expf(v1 - m);
    float s = e0 + e1;
#pragma unroll
    for (int d = 1; d < 64; d <<= 1) s += __shfl_xor(s, d);
    if (lane == 0) {
      mch[blk * 16 + wid] = m;
      lch[blk * 16 + wid] = s;
    }
    float* ep = es + ((size_t)blk * 128 + 2 * lane) * 16 + wid;  // es[blk][s][n]
    ep[0] = e0;
    ep[16] = e1;
  }
  __syncthreads();  // drains vmcnt -> es visible block-wide via L2

  // ---- Phase C: wp[blk][n][c] = sum_s e[s][n]*x[s][c]; thread <-> c ----
  {
    float acc[16];
#pragma unroll
    for (int n = 0; n < 16; ++n) acc[n] = 0.f;
    const float* xp = x + (size_t)srow0 * 1024 + tid;
    const float* eb = es + (size_t)blk * 2048;
#pragma unroll 2
    for (int s = 0; s < 128; ++s) {
      const float xv = xp[(size_t)s * 1024];
      const float4 e0 = *(const float4*)(eb + s * 16);
      const float4 e1 = *(const float4*)(eb + s * 16 + 4);
      const float4 e2 = *(const float4*)(eb + s * 16 + 8);
      const float4 e3 = *(const float4*)(eb + s * 16 + 12);
      acc[0]  += xv * e0.x; acc[1]  += xv * e0.y; acc[2]  += xv * e0.z; acc[3]  += xv * e0.w;
      acc[4]  += xv * e1.x; acc[5]  += xv * e1.y; acc[6]  += xv * e1.z; acc[7]  += xv * e1.w;
      acc[8]  += xv * e2.x; acc[9]  += xv * e2.y; acc[10] += xv * e2.z; acc[11] += xv * e2.w;
      acc[12] += xv * e3.x; acc[13] += xv * e3.y; acc[14] += xv * e3.z; acc[15] += xv * e3.w;
    }
    float* wpp = wp + (size_t)blk * 16384 + tid;
#pragma unroll
    for (int n = 0; n < 16; ++n) wpp[(size_t)n * 1024] = acc[n];
  }
}

// ---------------- K3: out = (sum_ch fac*wp . vk)/lg + vb ----------------
__global__ __launch_bounds__(256) void k_out(const float* __restrict__ wp,
                                             const float* __restrict__ vk,
                                             const float* __restrict__ vb,
                                             const float* __restrict__ mch,
                                             const float* __restrict__ lch,
                                             float* __restrict__ out) {
  const int bi = blockIdx.x;  // b*16+n, 512 blocks
  const int b = bi >> 4, n = bi & 15;
  const int tid = threadIdx.x;
  __shared__ float wrow[1024];
  __shared__ float red[4][64];

  // combine factors (identical on all threads; broadcast loads)
  float m8[8], l8[8];
#pragma unroll
  for (int ch = 0; ch < 8; ++ch) {
    m8[ch] = mch[(b * 8 + ch) * 16 + n];
    l8[ch] = lch[(b * 8 + ch) * 16 + n];
  }
  float mg = m8[0];
#pragma unroll
  for (int ch = 1; ch < 8; ++ch) mg = fmaxf(mg, m8[ch]);
  float fac[8], lg = 0.f;
#pragma unroll
  for (int ch = 0; ch < 8; ++ch) { fac[ch] = __expf(m8[ch] - mg); lg += fac[ch] * l8[ch]; }

  float4 a4 = {0.f, 0.f, 0.f, 0.f};
#pragma unroll
  for (int ch = 0; ch < 8; ch++) {
    const float4 t = *(const float4*)(wp + ((size_t)(b * 8 + ch) * 16 + n) * 1024 + tid * 4);
    a4.x += fac[ch] * t.x; a4.y += fac[ch] * t.y;
    a4.z += fac[ch] * t.z; a4.w += fac[ch] * t.w;
  }
  *(float4*)&wrow[tid * 4] = a4;
  __syncthreads();

  const int v = tid & 63, cq = tid >> 6;
  float a = 0.f;
  const float* vkc = vk + n * 64 + v;
  for (int ci = 0; ci < 256; ci++) {
    const int c = cq * 256 + ci;
    a += wrow[c] * vkc[(size_t)c * 1024];
  }
  red[cq][v] = a;
  __syncthreads();
  if (tid < 64) {
    const float o = (red[0][tid] + red[1][tid] + red[2][tid] + red[3][tid]) / lg
                    + vb[n * 64 + tid];
    out[(size_t)b * 1024 + n * 64 + tid] = o;
  }
}

extern "C" void kernel_launch(void* const* d_in, const int* in_sizes, int n_in,
                              void* d_out, int out_size, void* d_ws, size_t ws_size,
                              hipStream_t stream) {
  const float* x  = (const float*)d_in[0];  // key_value [32,32,32,1024]
  const float* q  = (const float*)d_in[1];  // query [1,1,16,64]
  const float* kk = (const float*)d_in[2];  // k_kernel [1024,1024]
  const float* kb = (const float*)d_in[3];  // k_bias [1024]
  const float* vk = (const float*)d_in[4];  // v_kernel [1024,1024]
  const float* vb = (const float*)d_in[5];  // v_bias [1024]
  float* out = (float*)d_out;               // [32,16,64] fp32

  float* f    = (float*)d_ws;
  float* qk   = f;             // 16384
  float* qb   = f + 16384;     // 16
  float* mch  = f + 16400;     // 4096   [b][ch][n]
  float* lch  = f + 20496;     // 4096
  float* es   = f + 24592;     // 524288 [blk][s][n]
  float* wp   = f + 548880;    // 4194304 [blk][n][c]   (total ~19 MB)

  hipLaunchKernelGGL(k_qk,    dim3(64),  dim3(256),  0, stream, kk, q, kb, qk, qb);
  hipLaunchKernelGGL(k_fused, dim3(256), dim3(1024), 0, stream, x, qk, qb, es, mch, lch, wp);
  hipLaunchKernelGGL(k_out,   dim3(512), dim3(256),  0, stream, wp, vk, vb, mch, lch, out);
}

// Round 7
// 68.937 us; speedup vs baseline: 1.6061x; 1.6061x over previous
//
#include <hip/hip_runtime.h>
#include <hip/hip_fp16.h>

// SimpleMHA2D: B=32, S=HW=1024, C=KV=1024, N=16, K=V=64, fp32.
//  K1: qk[c][n] = sum_k k_kernel[c][n*64+k]*q[n][k];  qb[n] = sum_k k_bias*q
//  K2 (fused, per 64-row chunk): logits (LDS qkt) -> chunk softmax in LDS
//      -> wp[blk][n][c] (fp16) via readlane-broadcast e.  Deferred rescale.
//  K3: out[b][n][v] = (sum_ch fac*wp . vk)/(sum_ch fac*l_ch) + vb.

__device__ __forceinline__ float rlane(float v, int l) {
  return __int_as_float(__builtin_amdgcn_readlane(__float_as_int(v), l));
}

// ---------------- K1: fold query into k_kernel ----------------
__global__ __launch_bounds__(256) void k_qk(const float* __restrict__ kk,
                                            const float* __restrict__ q,
                                            const float* __restrict__ kb,
                                            float* __restrict__ qk,
                                            float* __restrict__ qb) {
  const int gid = blockIdx.x * 256 + threadIdx.x;   // 16384 = 1024c * 16n
  const int c = gid >> 4, n = gid & 15;
  float a = 0.f;
#pragma unroll
  for (int k4 = 0; k4 < 64; k4 += 4) {
    const float4 kv = *(const float4*)(kk + (size_t)c * 1024 + n * 64 + k4);
    const float4 qv = *(const float4*)(q + n * 64 + k4);
    a += kv.x * qv.x + kv.y * qv.y + kv.z * qv.z + kv.w * qv.w;
  }
  qk[gid] = a;  // layout [c][n]
  if (blockIdx.x == 0 && threadIdx.x < 16) {
    float s = 0.f;
    for (int k = 0; k < 64; k++) s += kb[threadIdx.x * 64 + k] * q[threadIdx.x * 64 + k];
    qb[threadIdx.x] = s;
  }
}

// ---------------- K2: fused logits + chunk softmax + weighted sum ----------------
// 512 blocks (32 b x 16 chunks of 64 rows), 512 thr (8 waves).
// LDS: qkt[4nq][1024c][4e] 64KB (read-only after staging) + et2[64s][17] 4.3KB.
__global__ __launch_bounds__(512, 4) void k_fused(const float* __restrict__ x,
                                                  const float* __restrict__ qk,
                                                  const float* __restrict__ qb,
                                                  float* __restrict__ mch,
                                                  float* __restrict__ lch,
                                                  __half* __restrict__ wph) {
  __shared__ float qkt[16384];
  __shared__ float et2[64 * 17 + 4];
  const int tid = threadIdx.x;
  const int lane = tid & 63;
  const int wid = tid >> 6;          // 0..7
  const int blk = blockIdx.x;        // b*16 + ch
  const int srow0 = blk * 64;        // global row base

  // stage qk[c][n] -> qkt[nq][c][e]
#pragma unroll
  for (int it = 0; it < 8; ++it) {
    const int g = it * 512 + tid;    // quad index 0..4095
    const float4 v = *(const float4*)(qk + (size_t)g * 4);
    *(float4*)&qkt[(g & 3) * 4096 + (g >> 2) * 4] = v;
  }
  __syncthreads();

  // ---- Phase A: logits for 64 rows (2 sweeps x 8 waves x 4 rows) ----
#pragma unroll 1
  for (int sweep = 0; sweep < 2; ++sweep) {
    const int rloc = sweep * 32 + wid * 4;
    const float* xw = x + (size_t)(srow0 + rloc) * 1024 + lane;

    float acc[4][16];
#pragma unroll
    for (int r = 0; r < 4; ++r)
#pragma unroll
      for (int n = 0; n < 16; ++n) acc[r][n] = 0.f;

    float xa[4], xb[4];
#pragma unroll
    for (int r = 0; r < 4; ++r) xa[r] = xw[(size_t)r * 1024];

#pragma unroll 1
    for (int st = 0; st < 16; st += 2) {
#pragma unroll
      for (int r = 0; r < 4; ++r) xb[r] = xw[(size_t)r * 1024 + (st + 1) * 64];
      {
        const int c4 = (st * 64 + lane) * 4;
#pragma unroll
        for (int nq = 0; nq < 4; ++nq) {
          const float4 qv = *(const float4*)&qkt[nq * 4096 + c4];
#pragma unroll
          for (int r = 0; r < 4; ++r) {
            acc[r][nq * 4 + 0] += xa[r] * qv.x;
            acc[r][nq * 4 + 1] += xa[r] * qv.y;
            acc[r][nq * 4 + 2] += xa[r] * qv.z;
            acc[r][nq * 4 + 3] += xa[r] * qv.w;
          }
        }
      }
      if (st + 2 < 16) {
#pragma unroll
        for (int r = 0; r < 4; ++r) xa[r] = xw[(size_t)r * 1024 + (st + 2) * 64];
      }
      {
        const int c4 = ((st + 1) * 64 + lane) * 4;
#pragma unroll
        for (int nq = 0; nq < 4; ++nq) {
          const float4 qv = *(const float4*)&qkt[nq * 4096 + c4];
#pragma unroll
          for (int r = 0; r < 4; ++r) {
            acc[r][nq * 4 + 0] += xb[r] * qv.x;
            acc[r][nq * 4 + 1] += xb[r] * qv.y;
            acc[r][nq * 4 + 2] += xb[r] * qv.z;
            acc[r][nq * 4 + 3] += xb[r] * qv.w;
          }
        }
      }
    }

    // register-only reduce-scatter butterfly (validated R5)
    const int b0 = lane & 1, b1 = (lane >> 1) & 1;
    const int b2 = (lane >> 2) & 1, b3 = (lane >> 3) & 1;
    float f[4];
#pragma unroll
    for (int r = 0; r < 4; ++r) {
      float u[8];
#pragma unroll
      for (int m = 0; m < 8; ++m) {
        const float keep = b0 ? acc[r][2 * m + 1] : acc[r][2 * m];
        const float give = b0 ? acc[r][2 * m]     : acc[r][2 * m + 1];
        u[m] = keep + __shfl_xor(give, 1);
      }
      float w[4];
#pragma unroll
      for (int p = 0; p < 4; ++p) {
        const float keep = b1 ? u[2 * p + 1] : u[2 * p];
        const float give = b1 ? u[2 * p]     : u[2 * p + 1];
        w[p] = keep + __shfl_xor(give, 2);
      }
      float z[2];
#pragma unroll
      for (int qq = 0; qq < 2; ++qq) {
        const float keep = b2 ? w[2 * qq + 1] : w[2 * qq];
        const float give = b2 ? w[2 * qq]     : w[2 * qq + 1];
        z[qq] = keep + __shfl_xor(give, 4);
      }
      {
        const float keep = b3 ? z[1] : z[0];
        const float give = b3 ? z[0] : z[1];
        float t = keep + __shfl_xor(give, 8);
        t += __shfl_xor(t, 16);
        t += __shfl_xor(t, 32);
        f[r] = t;
      }
    }
    const int rsel = lane >> 4;
    float val = (rsel == 0) ? f[0] : (rsel == 1) ? f[1] : (rsel == 2) ? f[2] : f[3];
    val += qb[lane & 15];
    et2[(rloc + rsel) * 17 + (lane & 15)] = val;   // et2[row][n]
  }
  __syncthreads();

  // ---- Phase B: chunk softmax per n (wave handles n = wid, wid+8) ----
#pragma unroll
  for (int t = 0; t < 2; ++t) {
    const int nn = wid + t * 8;
    const float v = et2[lane * 17 + nn];
    float m = v;
#pragma unroll
    for (int d = 1; d < 64; d <<= 1) m = fmaxf(m, __shfl_xor(m, d));
    const float e = __expf(v - m);
    float s = e;
#pragma unroll
    for (int d = 1; d < 64; d <<= 1) s += __shfl_xor(s, d);
    if (lane == 0) {
      mch[blk * 16 + nn] = m;
      lch[blk * 16 + nn] = s;
    }
    et2[lane * 17 + nn] = e;   // in-place, same thread -> no race
  }
  __syncthreads();

  // ---- Phase C: wp[blk][n][c] = sum_s e[s][n]*x[s][c], 2 c per thread ----
  {
    const int c0 = wid * 128 + lane;     // and c0+64
    float acc0[16], acc1[16];
#pragma unroll
    for (int n = 0; n < 16; ++n) { acc0[n] = 0.f; acc1[n] = 0.f; }
    const float* xp = x + (size_t)srow0 * 1024;

    // software pipeline: load group sg+1 while computing sg
    float e4 = et2[(lane >> 4) * 17 + (lane & 15)];
    float x0[4], x1[4];
#pragma unroll
    for (int ss = 0; ss < 4; ++ss) {
      x0[ss] = xp[(size_t)ss * 1024 + c0];
      x1[ss] = xp[(size_t)ss * 1024 + c0 + 64];
    }
#pragma unroll 1
    for (int sg = 0; sg < 16; ++sg) {
      float e4n = 0.f, x0n[4], x1n[4];
      if (sg < 15) {
        const int s0n = (sg + 1) * 4;
        e4n = et2[(s0n + (lane >> 4)) * 17 + (lane & 15)];
#pragma unroll
        for (int ss = 0; ss < 4; ++ss) {
          x0n[ss] = xp[(size_t)(s0n + ss) * 1024 + c0];
          x1n[ss] = xp[(size_t)(s0n + ss) * 1024 + c0 + 64];
        }
      }
#pragma unroll
      for (int ss = 0; ss < 4; ++ss) {
#pragma unroll
        for (int n = 0; n < 16; ++n) {
          const float ev = rlane(e4, ss * 16 + n);  // lane ss*16+n holds e[s0+ss][n]
          acc0[n] += ev * x0[ss];
          acc1[n] += ev * x1[ss];
        }
      }
      e4 = e4n;
#pragma unroll
      for (int ss = 0; ss < 4; ++ss) { x0[ss] = x0n[ss]; x1[ss] = x1n[ss]; }
    }

    __half* wpp = wph + (size_t)blk * 16384;
#pragma unroll
    for (int n = 0; n < 16; ++n) {
      wpp[n * 1024 + c0]      = __float2half(acc0[n]);
      wpp[n * 1024 + c0 + 64] = __float2half(acc1[n]);
    }
  }
}

// ---------------- K3: out = (sum_ch fac*wp . vk)/lg + vb ----------------
__global__ __launch_bounds__(256) void k_out(const __half* __restrict__ wph,
                                             const float* __restrict__ vk,
                                             const float* __restrict__ vb,
                                             const float* __restrict__ mch,
                                             const float* __restrict__ lch,
                                             float* __restrict__ out) {
  const int bi = blockIdx.x;  // b*16+n, 512 blocks
  const int b = bi >> 4, n = bi & 15;
  const int tid = threadIdx.x;
  __shared__ float wrow[1024];
  __shared__ float red[4][64];

  // combine factors over 16 chunks (uniform scalar loads)
  float m16[16], l16[16];
#pragma unroll
  for (int ch = 0; ch < 16; ++ch) {
    m16[ch] = mch[(b * 16 + ch) * 16 + n];
    l16[ch] = lch[(b * 16 + ch) * 16 + n];
  }
  float mg = m16[0];
#pragma unroll
  for (int ch = 1; ch < 16; ++ch) mg = fmaxf(mg, m16[ch]);
  float fac[16], lg = 0.f;
#pragma unroll
  for (int ch = 0; ch < 16; ++ch) { fac[ch] = __expf(m16[ch] - mg); lg += fac[ch] * l16[ch]; }

  float4 a4 = {0.f, 0.f, 0.f, 0.f};
#pragma unroll
  for (int ch = 0; ch < 16; ch++) {
    const __half2* p = (const __half2*)(wph + ((size_t)(b * 16 + ch) * 16 + n) * 1024 + tid * 4);
    const float2 f01 = __half22float2(p[0]);
    const float2 f23 = __half22float2(p[1]);
    a4.x += fac[ch] * f01.x; a4.y += fac[ch] * f01.y;
    a4.z += fac[ch] * f23.x; a4.w += fac[ch] * f23.y;
  }
  *(float4*)&wrow[tid * 4] = a4;
  __syncthreads();

  const int v = tid & 63, cq = tid >> 6;
  float a = 0.f;
  const float* vkc = vk + n * 64 + v;
  for (int ci = 0; ci < 256; ci++) {
    const int c = cq * 256 + ci;
    a += wrow[c] * vkc[(size_t)c * 1024];
  }
  red[cq][v] = a;
  __syncthreads();
  if (tid < 64) {
    const float o = (red[0][tid] + red[1][tid] + red[2][tid] + red[3][tid]) / lg
                    + vb[n * 64 + tid];
    out[(size_t)b * 1024 + n * 64 + tid] = o;
  }
}

extern "C" void kernel_launch(void* const* d_in, const int* in_sizes, int n_in,
                              void* d_out, int out_size, void* d_ws, size_t ws_size,
                              hipStream_t stream) {
  const float* x  = (const float*)d_in[0];  // key_value [32,32,32,1024]
  const float* q  = (const float*)d_in[1];  // query [1,1,16,64]
  const float* kk = (const float*)d_in[2];  // k_kernel [1024,1024]
  const float* kb = (const float*)d_in[3];  // k_bias [1024]
  const float* vk = (const float*)d_in[4];  // v_kernel [1024,1024]
  const float* vb = (const float*)d_in[5];  // v_bias [1024]
  float* out = (float*)d_out;               // [32,16,64] fp32

  float*  f   = (float*)d_ws;
  float*  qk  = f;             // 16384
  float*  qb  = f + 16384;     // 16
  float*  mch = f + 16400;     // 8192  [b][ch16][n]
  float*  lch = f + 24592;     // 8192
  __half* wph = (__half*)(f + 32784);  // 8388608 halves = 16 MB; total ~16.2 MB

  hipLaunchKernelGGL(k_qk,    dim3(64),  dim3(256), 0, stream, kk, q, kb, qk, qb);
  hipLaunchKernelGGL(k_fused, dim3(512), dim3(512), 0, stream, x, qk, qb, mch, lch, wph);
  hipLaunchKernelGGL(k_out,   dim3(512), dim3(256), 0, stream, wph, vk, vb, mch, lch, out);
}